// Round 11
// baseline (187.180 us; speedup 1.0000x reference)
//
#include <hip/hip_runtime.h>

// out[t*768 + e] = weight[e*VOCAB + x[t]]
// memset(cur+spill_cnt+tcnt) -> scatter tokens into fixed-cap per-window
// buckets (32-col windows, cap 64, mean 10.4; overflow -> spill list) ->
// persistent gather (grid 2048 = 8 blocks/CU): block b serves XCD slice rows
// [(b&7)*96, +96); wids come from a per-XCD work-stealing counter (load
// balance; monotone order keeps wid/wid+1 boundary lines L2-adjacent).
// Per tile: commit prefetched 96x32 f32 slab into TRANSPOSED LDS
// (lds[c*98+r]; serve reads bank 2c+lane = 2-way free, staging writes 2-way
// free), issue next tile's global loads (fly under serve), serve bucket
// tokens with 256B-coalesced nontemporal stores. Blocks 0..63 drain the
// spill list first (no-op on random data).

#define VOCAB 50257
#define EMBED 768
#define WINB 32
#define NWIN 1571          // ceil(VOCAB/32)
#define ROWS 96            // EMBED / 8; row group == XCD id (b&7)
#define RSTRIDE 98         // transposed LDS col stride; 98%32=2 -> conflict-free
#define CAP 64             // bucket capacity (mean load 10.4)
#define NBLK 2048          // 8 blocks/CU x 256 CU

__global__ __launch_bounds__(256) void scatter_kernel(const int* __restrict__ x,
                                                      int* __restrict__ cur,
                                                      int* __restrict__ buckets,
                                                      int* __restrict__ spill_cnt,
                                                      int* __restrict__ spill,
                                                      int n) {
  int i = blockIdx.x * blockDim.x + threadIdx.x;
  if (i < n) {
    int v = x[i];
    int win = v >> 5;
    int p = atomicAdd(&cur[win], 1);
    if (p < CAP) {
      buckets[win * CAP + p] = (i << 5) | (v & 31);
    } else {
      int s = atomicAdd(spill_cnt, 1);
      spill[s] = (i << 16) | v;       // t:14b | v:16b
    }
  }
}

__global__ __launch_bounds__(256) void gather_kernel(const float* __restrict__ w,
                                                     const int* __restrict__ cur,
                                                     const int* __restrict__ buckets,
                                                     const int* __restrict__ spill_cnt,
                                                     const int* __restrict__ spill,
                                                     int* __restrict__ tcnt,
                                                     float* __restrict__ out) {
  __shared__ float lds[WINB * RSTRIDE];   // 12.5 KB, transposed: lds[c*98 + r]
  __shared__ int toks[CAP];
  __shared__ int s_wid;
  const int tid = threadIdx.x;
  const int b = blockIdx.x;

  // --- adversarial-only spill drain (spill_cnt==0 on random data) ---
  if (b < 64) {
    int cnt = *spill_cnt;
    for (int s = b; s < cnt; s += 64) {
      int pk = spill[s];
      int t = pk >> 16, v = pk & 0xFFFF;
      for (int e = tid; e < EMBED; e += 256)
        out[(size_t)t * EMBED + e] = w[(size_t)e * VOCAB + v];
    }
  }

  const int xcd = b & 7;
  const int row0 = xcd * ROWS;        // XCD owns a contiguous 19MB row slice
  const int wave = tid >> 6, lane = tid & 63;
  const int rr = tid >> 3, g4 = (tid & 7) << 2;  // rr in [0,32), g4 in {0..28}

  float4 pf0, pf1, pf2;               // prefetched slab granules (rows rr,+32,+64)
  int ptk = 0, pcnt = 0;              // prefetched token word + bucket count

  auto issue = [&](int wid) {
    const float* base = w + (size_t)(row0 + rr) * VOCAB + wid * WINB + g4;
    if (wid != NWIN - 1) {
      pf0 = *(const float4*)(base);
      pf1 = *(const float4*)(base + (size_t)32 * VOCAB);
      pf2 = *(const float4*)(base + (size_t)64 * VOCAB);
    } else {
      float* p0 = (float*)&pf0; float* p1 = (float*)&pf1; float* p2 = (float*)&pf2;
      for (int u = 0; u < 4; ++u) {
        bool ok = wid * WINB + g4 + u < VOCAB;
        p0[u] = ok ? base[u] : 0.f;
        p1[u] = ok ? base[(size_t)32 * VOCAB + u] : 0.f;
        p2[u] = ok ? base[(size_t)64 * VOCAB + u] : 0.f;
      }
    }
    if (tid < CAP) ptk = buckets[wid * CAP + tid];
    pcnt = cur[wid];                  // uniform
  };

  // prologue: steal first wid, prefetch it
  if (tid == 0) s_wid = atomicAdd(&tcnt[xcd], 1);
  __syncthreads();
  int wid = s_wid;
  if (wid >= NWIN) return;
  issue(wid);

  while (wid < NWIN) {
    __syncthreads();                  // previous serve done with lds/toks
    // commit slab transposed: granule (row 32k+rr, cols g4..g4+3)
    {
      float* c0 = &lds[(g4 + 0) * RSTRIDE + rr];
      float* c1 = &lds[(g4 + 1) * RSTRIDE + rr];
      float* c2 = &lds[(g4 + 2) * RSTRIDE + rr];
      float* c3 = &lds[(g4 + 3) * RSTRIDE + rr];
      c0[0]  = pf0.x; c1[0]  = pf0.y; c2[0]  = pf0.z; c3[0]  = pf0.w;
      c0[32] = pf1.x; c1[32] = pf1.y; c2[32] = pf1.z; c3[32] = pf1.w;
      c0[64] = pf2.x; c1[64] = pf2.y; c2[64] = pf2.z; c3[64] = pf2.w;
    }
    if (tid < CAP) toks[tid] = ptk;
    int mcnt = pcnt > CAP ? CAP : pcnt;
    if (tid == 0) s_wid = atomicAdd(&tcnt[xcd], 1);   // steal next wid
    __syncthreads();                  // commit + s_wid visible
    int wid_next = s_wid;
    if (wid_next < NWIN) issue(wid_next);   // next tile's loads fly under serve

    for (int i = wave; i < mcnt; i += 4) {
      int pk = toks[i];               // LDS broadcast
      int t = pk >> 5, c = pk & 31;
      float* o = &out[(size_t)t * EMBED + row0];
      __builtin_nontemporal_store(lds[c * RSTRIDE + lane], &o[lane]);
      if (lane < ROWS - 64)
        __builtin_nontemporal_store(lds[c * RSTRIDE + 64 + lane], &o[64 + lane]);
    }
    wid = wid_next;
  }
}

extern "C" void kernel_launch(void* const* d_in, const int* in_sizes, int n_in,
                              void* d_out, int out_size, void* d_ws, size_t ws_size,
                              hipStream_t stream) {
  const int*   x = (const int*)d_in[0];
  const float* w = (const float*)d_in[1];
  float* out = (float*)d_out;
  const int n = in_sizes[0];          // 16384 tokens

  int* cur       = (int*)d_ws;        // [NWIN]
  int* spill_cnt = cur + NWIN;        // [1]
  int* tcnt      = spill_cnt + 1;     // [8] per-XCD work counters
  int* spill     = tcnt + 8;          // [n]
  int* buckets   = spill + n;         // [NWIN*CAP]

  hipMemsetAsync(cur, 0, (NWIN + 1 + 8) * sizeof(int), stream);
  scatter_kernel<<<(n + 255) / 256, 256, 0, stream>>>(x, cur, buckets,
                                                      spill_cnt, spill, n);
  gather_kernel<<<NBLK, 256, 0, stream>>>(w, cur, buckets,
                                          spill_cnt, spill, tcnt, out);
}

// Round 12
// 46.154 us; speedup vs baseline: 4.0556x; 4.0556x over previous
//
#include <hip/hip_runtime.h>

// out[t*768 + e] = weight[e*VOCAB + x[t]]
// memset -> scatter tokens into fixed-cap per-window buckets (32-col windows,
// cap 64, mean 10.4; overflow -> spill list) -> gather: 25136 blocks of 128
// threads, one (48-row, 32-col window) tile each => 16 blocks/CU = 16
// independent tile pipelines per CU (2x R10's MLP). Stage slab into
// TRANSPOSED LDS (lds[c*50+r]: serve reads and staging writes both <=2-way,
// free), serve bucket tokens with 192B nontemporal stores. XCD-chunked
// swizzle: 25136/8 = 2*1571, so XCD k owns rows [k*96,+96) = contiguous 19MB
// weight slice with wids adjacent in time. Blocks 0..63 drain the spill list
// (no-op on random data).

#define VOCAB 50257
#define EMBED 768
#define WINB 32
#define NWIN 1571          // ceil(VOCAB/32); prime
#define RG 16              // row groups of 48
#define ROWS 48            // EMBED / RG
#define RST 50             // transposed col stride; (2c+r) banks -> <=2-way
#define CAP 64             // bucket capacity (mean load 10.4)

__global__ __launch_bounds__(256) void scatter_kernel(const int* __restrict__ x,
                                                      int* __restrict__ cur,
                                                      int* __restrict__ buckets,
                                                      int* __restrict__ spill_cnt,
                                                      int* __restrict__ spill,
                                                      int n) {
  int i = blockIdx.x * blockDim.x + threadIdx.x;
  if (i < n) {
    int v = x[i];
    int win = v >> 5;
    int p = atomicAdd(&cur[win], 1);
    if (p < CAP) {
      buckets[win * CAP + p] = (i << 5) | (v & 31);
    } else {
      int s = atomicAdd(spill_cnt, 1);
      spill[s] = (i << 16) | v;       // t:14b | v:16b
    }
  }
}

__device__ __forceinline__ int xcd_swizzle(int bid, int nwg) {
  const int NX = 8;                   // nwg % 8 == 0 here -> simple bijection
  int q = nwg / NX;
  return (bid % NX) * q + bid / NX;
}

__global__ __launch_bounds__(128) void gather_kernel(const float* __restrict__ w,
                                                     const int* __restrict__ cur,
                                                     const int* __restrict__ buckets,
                                                     const int* __restrict__ spill_cnt,
                                                     const int* __restrict__ spill,
                                                     float* __restrict__ out) {
  __shared__ float lds[WINB * RST];   // 6.4 KB, transposed: lds[c*50 + r]
  __shared__ int toks[CAP];
  const int tid = threadIdx.x;
  const int b = blockIdx.x;

  // --- adversarial-only spill drain (spill_cnt==0 on random data) ---
  if (b < 64) {
    int cnt = *spill_cnt;
    for (int s = b; s < cnt; s += 64) {
      int pk = spill[s];
      int t = pk >> 16, v = pk & 0xFFFF;
      for (int e = tid; e < EMBED; e += 128)
        out[(size_t)t * EMBED + e] = w[(size_t)e * VOCAB + v];
    }
  }

  const int logical = xcd_swizzle(b, RG * NWIN);
  const int rg  = logical / NWIN;     // 0..15; XCD k owns rg {2k, 2k+1}
  const int wid = logical % NWIN;     // adjacent in time within an XCD
  const int row0 = rg * ROWS;
  const int col0 = wid * WINB;

  int pcnt = cur[wid];                // uniform scalar load
  if (tid < CAP) toks[tid] = buckets[wid * CAP + tid];

  // --- stage 48x32 slab transposed: 3 granules/thread ---
  if (wid != NWIN - 1) {
    #pragma unroll
    for (int k = 0; k < 3; ++k) {
      int j = k * 128 + tid;
      int r = j >> 3, g4 = (j & 7) << 2;
      float4 v = *(const float4*)&w[(size_t)(row0 + r) * VOCAB + col0 + g4];
      lds[(g4 + 0) * RST + r] = v.x;  // bank (8g+2u+r)%32 within wave: <=2-way
      lds[(g4 + 1) * RST + r] = v.y;
      lds[(g4 + 2) * RST + r] = v.z;
      lds[(g4 + 3) * RST + r] = v.w;
    }
  } else {
    #pragma unroll
    for (int k = 0; k < 3; ++k) {
      int j = k * 128 + tid;
      int r = j >> 3, g4 = (j & 7) << 2;
      for (int u = 0; u < 4; ++u) {
        int c = col0 + g4 + u;
        lds[(g4 + u) * RST + r] = (c < VOCAB)
            ? w[(size_t)(row0 + r) * VOCAB + c] : 0.f;
      }
    }
  }
  __syncthreads();

  // --- serve bucket tokens; 192B-coalesced nontemporal stores ---
  int mcnt = pcnt > CAP ? CAP : pcnt;
  const int wave = tid >> 6, lane = tid & 63;
  for (int i = wave; i < mcnt; i += 2) {
    int pk = toks[i];                 // LDS broadcast
    int t = pk >> 5, c = pk & 31;
    if (lane < ROWS)                  // reads lds[c*50+lane]: <=2-way, free
      __builtin_nontemporal_store(lds[c * RST + lane],
                                  &out[(size_t)t * EMBED + row0 + lane]);
  }
}

extern "C" void kernel_launch(void* const* d_in, const int* in_sizes, int n_in,
                              void* d_out, int out_size, void* d_ws, size_t ws_size,
                              hipStream_t stream) {
  const int*   x = (const int*)d_in[0];
  const float* w = (const float*)d_in[1];
  float* out = (float*)d_out;
  const int n = in_sizes[0];          // 16384 tokens

  int* cur       = (int*)d_ws;        // [NWIN]
  int* spill_cnt = cur + NWIN;        // [1] (contiguous with cur for memset)
  int* spill     = spill_cnt + 1;     // [n]
  int* buckets   = spill + n;         // [NWIN*CAP]

  hipMemsetAsync(cur, 0, (NWIN + 1) * sizeof(int), stream);
  scatter_kernel<<<(n + 255) / 256, 256, 0, stream>>>(x, cur, buckets,
                                                      spill_cnt, spill, n);
  gather_kernel<<<RG * NWIN, 128, 0, stream>>>(w, cur, buckets,
                                               spill_cnt, spill, out);
}